// Round 4
// baseline (2274.246 us; speedup 1.0000x reference)
//
#include <hip/hip_runtime.h>

// ---------------------------------------------------------------------------
// Bidirectional 2-layer GRU (B=256, L=200, IN=512, H=256) + FC heads.
// R4: k_gru = 4 waves/block (1/SIMD, waves_per_eu(1,1), 512-reg budget),
//     ALL 3 gates' weights pinned VGPR-resident via asm("+v") (384 regs/wave)
//     -- kills the per-step 393KB L2 weight re-stream that bounded R1-R3.
//     xi in stride-772 LDS (conflict-free epilogue reads); hprev via LDS;
//     r/z biases folded into gemm bias.
// ---------------------------------------------------------------------------

typedef _Float16 half8 __attribute__((ext_vector_type(8)));
typedef _Float16 half4v __attribute__((ext_vector_type(4)));
typedef float fx4 __attribute__((ext_vector_type(4)));

#define BATCH 256
#define SEQ   200
#define HID   256
#define MROWS (BATCH*SEQ)   // 51200
#define NG    1536          // 3H * 2 directions
#define KDIM  512

#define XSTRIDE 772         // xi LDS row stride (halves): 386 dw == 2 mod 8 -> bank spread
#define HSTRIDE 264         // h LDS row stride (halves): 16B-aligned rows

__device__ __forceinline__ void gload_lds16(const _Float16* g, _Float16* l) {
  __builtin_amdgcn_global_load_lds((const __attribute__((address_space(1))) void*)g,
                                   (__attribute__((address_space(3))) void*)l, 16, 0, 0);
}

// ---------------------------- prep kernels ---------------------------------

__global__ __launch_bounds__(256) void k_cast_x(const float4* __restrict__ x,
                                                half4v* __restrict__ xh, int n4) {
  int i = blockIdx.x * 256 + threadIdx.x;
  if (i < n4) {
    float4 v = x[i];
    half4v o;
    o[0] = (_Float16)v.x; o[1] = (_Float16)v.y; o[2] = (_Float16)v.z; o[3] = (_Float16)v.w;
    xh[i] = o;
  }
}

// Concat input-projection weights [1536][512] fp16; bias = bih + (bhh for r,z only)
__global__ __launch_bounds__(256) void k_prep_wih(const float* __restrict__ wf,
                                                  const float* __restrict__ wr,
                                                  const float* __restrict__ bf_,
                                                  const float* __restrict__ br_,
                                                  const float* __restrict__ bhf,
                                                  const float* __restrict__ bhr,
                                                  _Float16* __restrict__ wcat,
                                                  float* __restrict__ bcat) {
  int idx = blockIdx.x * 256 + threadIdx.x;     // < 1536*512
  int n = idx >> 9;
  float v = (n < 768) ? wf[idx] : wr[idx - 768 * 512];
  wcat[idx] = (_Float16)v;
  if (idx < 1536) {
    float b;
    if (idx < 768) b = bf_[idx] + ((idx < 512) ? bhf[idx] : 0.f);
    else { int i2 = idx - 768; b = br_[i2] + ((i2 < 512) ? bhr[i2] : 0.f); }
    bcat[idx] = b;
  }
}

// Pack w_hh into MFMA B-fragment order: [dir][T(16)][gate(3)][kf(8)][lane(64)][i(8)]
__global__ __launch_bounds__(256) void k_prep_whh(const float* __restrict__ whf,
                                                  const float* __restrict__ whr,
                                                  _Float16* __restrict__ whp) {
  int e = blockIdx.x * 256 + threadIdx.x;       // < 2*196608
  int dir = e / 196608;
  int r = e - dir * 196608;
  int w = r / 12288;  int r2 = r - w * 12288;
  int gate = r2 >> 12; int r3 = r2 & 4095;
  int kf = r3 >> 9;    int r4 = r3 & 511;
  int lane = r4 >> 3;  int i = r4 & 7;
  int row = gate * 256 + w * 16 + (lane & 15);
  int col = kf * 32 + (lane >> 4) * 8 + i;
  const float* src = dir ? whr : whf;
  whp[e] = (_Float16)src[row * 256 + col];
}

// ---------------------------- xi GEMM (m97 structure) ----------------------
__global__ __launch_bounds__(256) void k_gemm(const _Float16* __restrict__ A,
                                              const _Float16* __restrict__ Wt,
                                              const float* __restrict__ bias,
                                              _Float16* __restrict__ C) {
  __shared__ __align__(16) _Float16 As[128 * 32];
  __shared__ __align__(16) _Float16 Bs[128 * 32];
  const int tid = threadIdx.x;
  const int wv = tid >> 6, ln = tid & 63;
  const int wm = wv >> 1, wn = wv & 1;
  const int jl = ln & 15, q = ln >> 4;
  const int m0 = blockIdx.x * 128, n0 = blockIdx.y * 128;

  const int r0 = tid >> 2, k80 = (tid & 3) * 8;
  const int r1 = r0 + 64;

  fx4 acc[4][4];
#pragma unroll
  for (int a = 0; a < 4; ++a)
#pragma unroll
    for (int b = 0; b < 4; ++b) acc[a][b] = (fx4){0.f, 0.f, 0.f, 0.f};

  for (int kk = 0; kk < KDIM; kk += 32) {
    gload_lds16(A  + (size_t)(m0 + r0) * KDIM + kk + k80, As + tid * 8);
    gload_lds16(A  + (size_t)(m0 + r1) * KDIM + kk + k80, As + (tid + 256) * 8);
    gload_lds16(Wt + (size_t)(n0 + r0) * KDIM + kk + k80, Bs + tid * 8);
    gload_lds16(Wt + (size_t)(n0 + r1) * KDIM + kk + k80, Bs + (tid + 256) * 8);
    __syncthreads();
    half8 af[4], bfr[4];
#pragma unroll
    for (int mt = 0; mt < 4; ++mt)
      af[mt] = *(const half8*)(As + (wm * 64 + mt * 16 + jl) * 32 + q * 8);
#pragma unroll
    for (int nt = 0; nt < 4; ++nt)
      bfr[nt] = *(const half8*)(Bs + (wn * 64 + nt * 16 + jl) * 32 + q * 8);
#pragma unroll
    for (int mt = 0; mt < 4; ++mt)
#pragma unroll
      for (int nt = 0; nt < 4; ++nt)
        acc[mt][nt] = __builtin_amdgcn_mfma_f32_16x16x32_f16(af[mt], bfr[nt], acc[mt][nt], 0, 0, 0);
    __syncthreads();
  }

  float bsv[4];
#pragma unroll
  for (int nt = 0; nt < 4; ++nt) bsv[nt] = bias[n0 + wn * 64 + nt * 16 + jl];

  for (int mt = 0; mt < 4; ++mt) {
#pragma unroll
    for (int nt = 0; nt < 4; ++nt)
#pragma unroll
      for (int rg = 0; rg < 4; ++rg)
        As[(wm * 16 + q * 4 + rg) * 128 + wn * 64 + nt * 16 + jl] =
            (_Float16)(acc[mt][nt][rg] + bsv[nt]);
    __syncthreads();
#pragma unroll
    for (int i = 0; i < 2; ++i) {
      int idx = i * 256 + tid;
      int rl = idx >> 4, c8 = idx & 15;
      int grow = m0 + (rl >> 4) * 64 + mt * 16 + (rl & 15);
      *(half8*)(C + (size_t)grow * NG + n0 + c8 * 8) = *(const half8*)(As + rl * 128 + c8 * 8);
    }
    __syncthreads();
  }
}

// ---------------------------- GRU recurrence -------------------------------
// 32 blocks (16 batch-tiles x 2 dirs) x 256 threads (4 waves, 1/SIMD).
// Wave w owns hidden j in [64w, 64w+64) = 4 tiles x 3 gates x 8 kf = 96 half8
// weight fragments, pinned in VGPRs via asm (not rematerializable).
__global__ __launch_bounds__(256) __attribute__((amdgpu_waves_per_eu(1, 1)))
void k_gru(const _Float16* __restrict__ xi,
           const _Float16* __restrict__ whp,
           const float* __restrict__ bhhf,
           const float* __restrict__ bhhr,
           _Float16* __restrict__ out) {
  extern __shared__ _Float16 smem[];
  _Float16* X0 = smem;                        // 16*772 = 12352 halves
  _Float16* X1 = smem + 12352;
  _Float16* H0 = smem + 24704;                // 16*264 = 4224 halves
  _Float16* H1 = smem + 28928;                // total 33152 halves = 66304 B

  const int tid = threadIdx.x, w = tid >> 6, ln = tid & 63;
  const int jl = ln & 15, q = ln >> 4;
  const int bt = blockIdx.x, dir = blockIdx.y;
  const float* bhh = dir ? bhhr : bhhf;

  // ---- xi staging: 1536 16B-chunks per step; 6 per thread ----
  const long long t0 = dir ? (SEQ - 1) : 0;
  const int xstep = dir ? -NG : NG;
  const _Float16* gp[6];
  int lo[6];
#pragma unroll
  for (int k = 0; k < 6; ++k) {
    int c = k * 256 + tid;
    int row = c / 96, cc = c - row * 96;
    gp[k] = xi + ((size_t)((bt * 16 + row) * SEQ) + t0) * NG + dir * 768 + cc * 8;
    lo[k] = row * XSTRIDE + cc * 8;
  }
  half8 xv[6];
#pragma unroll
  for (int k = 0; k < 6; ++k) xv[k] = *(const half8*)gp[k];   // xi(t0)

  // ---- resident weights: 4 tiles x 3 gates x 8 kf = 96 half8 = 384 VGPRs ----
  half8 wf[4][3][8];
#pragma unroll
  for (int tt = 0; tt < 4; ++tt)
#pragma unroll
    for (int g = 0; g < 3; ++g)
#pragma unroll
      for (int kf = 0; kf < 8; ++kf) {
        wf[tt][g][kf] = *(const half8*)(whp + ((size_t)(dir * 16 + w * 4 + tt)) * 12288
                                        + g * 4096 + kf * 512 + ln * 8);
        asm volatile("" : "+v"(wf[tt][g][kf]));   // pin: opaque def, no remat
      }
  float bhn[4];
#pragma unroll
  for (int tt = 0; tt < 4; ++tt) bhn[tt] = bhh[512 + w * 64 + tt * 16 + jl];

  for (int i = tid; i < 4224; i += 256) H0[i] = (_Float16)0.f;
#pragma unroll
  for (int k = 0; k < 6; ++k) {     // xi(t0) -> X0 (b64 pairs: rows 8B-aligned)
    half4v lo4 = __builtin_shufflevector(xv[k], xv[k], 0, 1, 2, 3);
    half4v hi4 = __builtin_shufflevector(xv[k], xv[k], 4, 5, 6, 7);
    *(half4v*)(X0 + lo[k]) = lo4;
    *(half4v*)(X0 + lo[k] + 4) = hi4;
  }

  // ---- coalesced out-store mapping (1 step delayed) ----
  const int orow = tid >> 4, oc = tid & 15;
  _Float16* op = out + ((size_t)((bt * 16 + orow) * SEQ) + t0) * 512 + dir * 256 + oc * 8;
  const int ostep = dir ? -512 : 512;
  const int obase = orow * HSTRIDE + oc * 8;

  __syncthreads();

  for (int t = 0; t < SEQ; ++t) {
    const _Float16* xr = (t & 1) ? X1 : X0;
    _Float16*       xw = (t & 1) ? X0 : X1;
    const _Float16* hr = (t & 1) ? H1 : H0;
    _Float16*       hw = (t & 1) ? H0 : H1;

    if (t < SEQ - 1) {                 // issue xi(t+1) loads; land during MFMA
#pragma unroll
      for (int k = 0; k < 6; ++k) { gp[k] += xstep; xv[k] = *(const half8*)gp[k]; }
    }
    if (t > 0) {                       // store h(t-1) (in hr) to global
      half8 v0 = *(const half8*)(hr + obase);
      half8 v1 = *(const half8*)(hr + obase + 128);
      *(half8*)op = v0;
      *(half8*)(op + 128) = v1;
      op += ostep;
    }

    fx4 acc[4][3];
#pragma unroll
    for (int tt = 0; tt < 4; ++tt)
#pragma unroll
      for (int g = 0; g < 3; ++g) acc[tt][g] = (fx4){0.f, 0.f, 0.f, 0.f};

#pragma unroll
    for (int kf = 0; kf < 8; ++kf) {
      half8 a = *(const half8*)(hr + jl * HSTRIDE + kf * 32 + q * 8);
#pragma unroll
      for (int tt = 0; tt < 4; ++tt)
#pragma unroll
        for (int g = 0; g < 3; ++g)
          acc[tt][g] = __builtin_amdgcn_mfma_f32_16x16x32_f16(a, wf[tt][g][kf], acc[tt][g], 0, 0, 0);
    }

    if (t < SEQ - 1) {                 // xi(t+1) -> xw
#pragma unroll
      for (int k = 0; k < 6; ++k) {
        half4v lo4 = __builtin_shufflevector(xv[k], xv[k], 0, 1, 2, 3);
        half4v hi4 = __builtin_shufflevector(xv[k], xv[k], 4, 5, 6, 7);
        *(half4v*)(xw + lo[k]) = lo4;
        *(half4v*)(xw + lo[k] + 4) = hi4;
      }
    }

#pragma unroll
    for (int tt = 0; tt < 4; ++tt) {
      const int col = w * 64 + tt * 16 + jl;
#pragma unroll
      for (int rg = 0; rg < 4; ++rg) {
        const int rr = q * 4 + rg;
        float ir  = (float)xr[rr * XSTRIDE + col];         // has bih_r + bhh_r
        float iz  = (float)xr[rr * XSTRIDE + 256 + col];   // has bih_z + bhh_z
        float inn = (float)xr[rr * XSTRIDE + 512 + col];   // has bih_n
        float rv = __builtin_amdgcn_rcpf(1.f + __expf(-(acc[tt][0][rg] + ir)));
        float zv = __builtin_amdgcn_rcpf(1.f + __expf(-(acc[tt][1][rg] + iz)));
        float gn = inn + rv * (acc[tt][2][rg] + bhn[tt]);
        gn = fminf(fmaxf(gn, -9.f), 9.f);
        float e2 = __expf(2.f * gn);
        float nn = (e2 - 1.f) * __builtin_amdgcn_rcpf(e2 + 1.f);
        float hp = (float)hr[rr * HSTRIDE + col];
        float h = zv * (hp - nn) + nn;
        hw[rr * HSTRIDE + col] = (_Float16)h;
      }
    }
    __syncthreads();
  }
  // flush h(SEQ-1): written by t=199 into H0
  half8 v0 = *(const half8*)(H0 + obase);
  half8 v1 = *(const half8*)(H0 + obase + 128);
  *(half8*)op = v0;
  *(half8*)(op + 128) = v1;
}

// ---------------------------- heads ----------------------------------------

__global__ __launch_bounds__(256) void k_heads1(const _Float16* __restrict__ out,
                                                const float* __restrict__ fc1w,
                                                const float* __restrict__ fc1b,
                                                const float* __restrict__ fc2w,
                                                const float* __restrict__ fc2b,
                                                float* __restrict__ y,
                                                float* __restrict__ y2) {
  int gw = (blockIdx.x * 256 + threadIdx.x) >> 6;
  int ln = threadIdx.x & 63;
  int b = gw / SEQ, t = gw - b * SEQ;
  half8 ov = *(const half8*)(out + (size_t)gw * 512 + ln * 8);
  float o[8];
#pragma unroll
  for (int i = 0; i < 8; ++i) o[i] = (float)ov[i];

  float4 w1a = *(const float4*)(fc1w + ln * 8);
  float4 w1b = *(const float4*)(fc1w + ln * 8 + 4);
  float s1 = o[0]*w1a.x + o[1]*w1a.y + o[2]*w1a.z + o[3]*w1a.w
           + o[4]*w1b.x + o[5]*w1b.y + o[6]*w1b.z + o[7]*w1b.w;
  float s2[10];
#pragma unroll
  for (int c = 0; c < 10; ++c) {
    float4 wa = *(const float4*)(fc2w + c * 512 + ln * 8);
    float4 wbv = *(const float4*)(fc2w + c * 512 + ln * 8 + 4);
    s2[c] = o[0]*wa.x + o[1]*wa.y + o[2]*wa.z + o[3]*wa.w
          + o[4]*wbv.x + o[5]*wbv.y + o[6]*wbv.z + o[7]*wbv.w;
  }
#pragma unroll
  for (int m = 32; m; m >>= 1) {
    s1 += __shfl_xor(s1, m);
#pragma unroll
    for (int c = 0; c < 10; ++c) s2[c] += __shfl_xor(s2[c], m);
  }
  if (ln == 0) {
    y[gw] = s1 + fc1b[0];
    float* y2p = y2 + (size_t)b * 2000 + t * 10;
#pragma unroll
    for (int c = 0; c < 10; ++c) y2p[c] = s2[c] + fc2b[c];
  }
}

__device__ __forceinline__ float blkRedMax(float v, float* red, int tid) {
#pragma unroll
  for (int m = 32; m; m >>= 1) v = fmaxf(v, __shfl_xor(v, m));
  __syncthreads();
  if ((tid & 63) == 0) red[tid >> 6] = v;
  __syncthreads();
  return fmaxf(fmaxf(red[0], red[1]), fmaxf(red[2], red[3]));
}
__device__ __forceinline__ float blkRedSum(float v, float* red, int tid) {
#pragma unroll
  for (int m = 32; m; m >>= 1) v += __shfl_xor(v, m);
  __syncthreads();
  if ((tid & 63) == 0) red[tid >> 6] = v;
  __syncthreads();
  return red[0] + red[1] + red[2] + red[3];
}

__global__ __launch_bounds__(256) void k_heads2(const float* __restrict__ y,
                                                const float* __restrict__ y2,
                                                float* __restrict__ y3) {
  __shared__ float sp[SEQ];
  __shared__ float se[2000];
  __shared__ float red[4];
  int b = blockIdx.x, tid = threadIdx.x;

  float v = (tid < SEQ) ? y[(size_t)b * SEQ + tid] : -3.0e38f;
  float mx = blkRedMax(v, red, tid);
  float e = (tid < SEQ) ? __expf(v - mx) : 0.f;
  float sum = blkRedSum(e, red, tid);
  if (tid < SEQ) sp[tid] = e / (sum * 10.f);

  float vv[8];
  float lm = -3.0e38f;
#pragma unroll
  for (int r = 0; r < 8; ++r) {
    int k = tid + r * 256;
    vv[r] = (k < 2000) ? y2[(size_t)b * 2000 + k] : -3.0e38f;
    lm = fmaxf(lm, vv[r]);
  }
  float mx2 = blkRedMax(lm, red, tid);
  float ls = 0.f;
#pragma unroll
  for (int r = 0; r < 8; ++r) {
    int k = tid + r * 256;
    if (k < 2000) { float ee = __expf(vv[r] - mx2); se[k] = ee; ls += ee; }
  }
  float sum2 = blkRedSum(ls, red, tid);
  __syncthreads();
  float inv = 1.f / sum2;
#pragma unroll
  for (int r = 0; r < 8; ++r) {
    int k = tid + r * 256;
    if (k < 2000) y3[(size_t)b * 2000 + k] = se[k] * inv + sp[k / 10];
  }
}

// ---------------------------- launch ---------------------------------------

extern "C" void kernel_launch(void* const* d_in, const int* in_sizes, int n_in,
                              void* d_out, int out_size, void* d_ws, size_t ws_size,
                              hipStream_t stream) {
  const float* x     = (const float*)d_in[0];
  const float* wih0  = (const float*)d_in[1];
  const float* whh0  = (const float*)d_in[2];
  const float* bih0  = (const float*)d_in[3];
  const float* bhh0  = (const float*)d_in[4];
  const float* wih0r = (const float*)d_in[5];
  const float* whh0r = (const float*)d_in[6];
  const float* bih0r = (const float*)d_in[7];
  const float* bhh0r = (const float*)d_in[8];
  const float* wih1  = (const float*)d_in[9];
  const float* whh1  = (const float*)d_in[10];
  const float* bih1  = (const float*)d_in[11];
  const float* bhh1  = (const float*)d_in[12];
  const float* wih1r = (const float*)d_in[13];
  const float* whh1r = (const float*)d_in[14];
  const float* bih1r = (const float*)d_in[15];
  const float* bhh1r = (const float*)d_in[16];
  const float* fc1w  = (const float*)d_in[17];
  const float* fc1b  = (const float*)d_in[18];
  const float* fc2w  = (const float*)d_in[19];
  const float* fc2b  = (const float*)d_in[20];

  char* ws = (char*)d_ws;
  _Float16* xh    = (_Float16*)(ws + 0);
  _Float16* xi    = (_Float16*)(ws + 52428800);
  _Float16* l0    = (_Float16*)(ws + 209715200);
  _Float16* outh  = (_Float16*)(ws + 262144000);
  _Float16* wcat0 = (_Float16*)(ws + 314572800);
  _Float16* wcat1 = (_Float16*)(ws + 316145664);
  _Float16* whp0  = (_Float16*)(ws + 317718528);
  _Float16* whp1  = (_Float16*)(ws + 318504960);
  float*    bcat0 = (float*)(ws + 319291392);
  float*    bcat1 = (float*)(ws + 319297536);

  float* y  = (float*)d_out;
  float* y2 = (float*)d_out + 51200;
  float* y3 = (float*)d_out + 563200;

  k_cast_x<<<25600, 256, 0, stream>>>((const float4*)x, (half4v*)xh, 6553600);
  k_prep_wih<<<3072, 256, 0, stream>>>(wih0, wih0r, bih0, bih0r, bhh0, bhh0r, wcat0, bcat0);
  k_prep_wih<<<3072, 256, 0, stream>>>(wih1, wih1r, bih1, bih1r, bhh1, bhh1r, wcat1, bcat1);
  k_prep_whh<<<1536, 256, 0, stream>>>(whh0, whh0r, whp0);
  k_prep_whh<<<1536, 256, 0, stream>>>(whh1, whh1r, whp1);

  hipFuncSetAttribute(reinterpret_cast<const void*>(k_gru),
                      hipFuncAttributeMaxDynamicSharedMemorySize, 66304);

  k_gemm<<<dim3(400, 12), 256, 0, stream>>>(xh, wcat0, bcat0, xi);
  k_gru<<<dim3(16, 2), 256, 66304, stream>>>(xi, whp0, bhh0, bhh0r, l0);
  k_gemm<<<dim3(400, 12), 256, 0, stream>>>(l0, wcat1, bcat1, xi);
  k_gru<<<dim3(16, 2), 256, 66304, stream>>>(xi, whp1, bhh1, bhh1r, outh);
  k_heads1<<<12800, 256, 0, stream>>>(outh, fc1w, fc1b, fc2w, fc2b, y, y2);
  k_heads2<<<256, 256, 0, stream>>>(y, y2, y3);
}

// Round 5
// 1353.696 us; speedup vs baseline: 1.6800x; 1.6800x over previous
//
#include <hip/hip_runtime.h>

// ---------------------------------------------------------------------------
// Bidirectional 2-layer GRU (B=256, L=200, IN=512, H=256) + FC heads.
// R5: k_gru = 8 waves (2/SIMD, 256-reg budget). r,z weights pinned in VGPRs
//     (128/wave, asm "+v" -- pin works per R4, and 128+working fits the 256
//     arch cap R4 exposed). n-gate weights in LDS (128 KB). h state in LDS
//     double-buffer with XOR-swizzled chunks (kills the 8-way A-frag bank
//     aliasing behind the 3-4M SQ_LDS_BANK_CONFLICT). xi register-prefetched.
// ---------------------------------------------------------------------------

typedef _Float16 half8 __attribute__((ext_vector_type(8)));
typedef _Float16 half4v __attribute__((ext_vector_type(4)));
typedef float fx4 __attribute__((ext_vector_type(4)));

#define BATCH 256
#define SEQ   200
#define HID   256
#define MROWS (BATCH*SEQ)   // 51200
#define NG    1536          // 3H * 2 directions
#define KDIM  512

__device__ __forceinline__ void gload_lds16(const _Float16* g, _Float16* l) {
  __builtin_amdgcn_global_load_lds((const __attribute__((address_space(1))) void*)g,
                                   (__attribute__((address_space(3))) void*)l, 16, 0, 0);
}

// ---------------------------- prep kernels ---------------------------------

__global__ __launch_bounds__(256) void k_cast_x(const float4* __restrict__ x,
                                                half4v* __restrict__ xh, int n4) {
  int i = blockIdx.x * 256 + threadIdx.x;
  if (i < n4) {
    float4 v = x[i];
    half4v o;
    o[0] = (_Float16)v.x; o[1] = (_Float16)v.y; o[2] = (_Float16)v.z; o[3] = (_Float16)v.w;
    xh[i] = o;
  }
}

// Concat input-projection weights [1536][512] fp16; bias = bih + (bhh for r,z only)
__global__ __launch_bounds__(256) void k_prep_wih(const float* __restrict__ wf,
                                                  const float* __restrict__ wr,
                                                  const float* __restrict__ bf_,
                                                  const float* __restrict__ br_,
                                                  const float* __restrict__ bhf,
                                                  const float* __restrict__ bhr,
                                                  _Float16* __restrict__ wcat,
                                                  float* __restrict__ bcat) {
  int idx = blockIdx.x * 256 + threadIdx.x;     // < 1536*512
  int n = idx >> 9;
  float v = (n < 768) ? wf[idx] : wr[idx - 768 * 512];
  wcat[idx] = (_Float16)v;
  if (idx < 1536) {
    float b;
    if (idx < 768) b = bf_[idx] + ((idx < 512) ? bhf[idx] : 0.f);
    else { int i2 = idx - 768; b = br_[i2] + ((i2 < 512) ? bhr[i2] : 0.f); }
    bcat[idx] = b;
  }
}

// Pack w_hh into MFMA B-fragment order: [dir][T(16)][gate(3)][kf(8)][lane(64)][i(8)]
__global__ __launch_bounds__(256) void k_prep_whh(const float* __restrict__ whf,
                                                  const float* __restrict__ whr,
                                                  _Float16* __restrict__ whp) {
  int e = blockIdx.x * 256 + threadIdx.x;       // < 2*196608
  int dir = e / 196608;
  int r = e - dir * 196608;
  int w = r / 12288;  int r2 = r - w * 12288;
  int gate = r2 >> 12; int r3 = r2 & 4095;
  int kf = r3 >> 9;    int r4 = r3 & 511;
  int lane = r4 >> 3;  int i = r4 & 7;
  int row = gate * 256 + w * 16 + (lane & 15);
  int col = kf * 32 + (lane >> 4) * 8 + i;
  const float* src = dir ? whr : whf;
  whp[e] = (_Float16)src[row * 256 + col];
}

// ---------------------------- xi GEMM (m97 structure) ----------------------
__global__ __launch_bounds__(256) void k_gemm(const _Float16* __restrict__ A,
                                              const _Float16* __restrict__ Wt,
                                              const float* __restrict__ bias,
                                              _Float16* __restrict__ C) {
  __shared__ __align__(16) _Float16 As[128 * 32];
  __shared__ __align__(16) _Float16 Bs[128 * 32];
  const int tid = threadIdx.x;
  const int wv = tid >> 6, ln = tid & 63;
  const int wm = wv >> 1, wn = wv & 1;
  const int jl = ln & 15, q = ln >> 4;
  const int m0 = blockIdx.x * 128, n0 = blockIdx.y * 128;

  const int r0 = tid >> 2, k80 = (tid & 3) * 8;
  const int r1 = r0 + 64;

  fx4 acc[4][4];
#pragma unroll
  for (int a = 0; a < 4; ++a)
#pragma unroll
    for (int b = 0; b < 4; ++b) acc[a][b] = (fx4){0.f, 0.f, 0.f, 0.f};

  for (int kk = 0; kk < KDIM; kk += 32) {
    gload_lds16(A  + (size_t)(m0 + r0) * KDIM + kk + k80, As + tid * 8);
    gload_lds16(A  + (size_t)(m0 + r1) * KDIM + kk + k80, As + (tid + 256) * 8);
    gload_lds16(Wt + (size_t)(n0 + r0) * KDIM + kk + k80, Bs + tid * 8);
    gload_lds16(Wt + (size_t)(n0 + r1) * KDIM + kk + k80, Bs + (tid + 256) * 8);
    __syncthreads();
    half8 af[4], bfr[4];
#pragma unroll
    for (int mt = 0; mt < 4; ++mt)
      af[mt] = *(const half8*)(As + (wm * 64 + mt * 16 + jl) * 32 + q * 8);
#pragma unroll
    for (int nt = 0; nt < 4; ++nt)
      bfr[nt] = *(const half8*)(Bs + (wn * 64 + nt * 16 + jl) * 32 + q * 8);
#pragma unroll
    for (int mt = 0; mt < 4; ++mt)
#pragma unroll
      for (int nt = 0; nt < 4; ++nt)
        acc[mt][nt] = __builtin_amdgcn_mfma_f32_16x16x32_f16(af[mt], bfr[nt], acc[mt][nt], 0, 0, 0);
    __syncthreads();
  }

  float bsv[4];
#pragma unroll
  for (int nt = 0; nt < 4; ++nt) bsv[nt] = bias[n0 + wn * 64 + nt * 16 + jl];

  for (int mt = 0; mt < 4; ++mt) {
#pragma unroll
    for (int nt = 0; nt < 4; ++nt)
#pragma unroll
      for (int rg = 0; rg < 4; ++rg)
        As[(wm * 16 + q * 4 + rg) * 128 + wn * 64 + nt * 16 + jl] =
            (_Float16)(acc[mt][nt][rg] + bsv[nt]);
    __syncthreads();
#pragma unroll
    for (int i = 0; i < 2; ++i) {
      int idx = i * 256 + tid;
      int rl = idx >> 4, c8 = idx & 15;
      int grow = m0 + (rl >> 4) * 64 + mt * 16 + (rl & 15);
      *(half8*)(C + (size_t)grow * NG + n0 + c8 * 8) = *(const half8*)(As + rl * 128 + c8 * 8);
    }
    __syncthreads();
  }
}

// ---------------------------- GRU recurrence -------------------------------
// 32 blocks (16 batch-tiles x 2 dirs) x 512 threads (8 waves, 2/SIMD).
// Wave w owns hidden [32w, 32w+32) = 2 tiles. r,z weights pinned in VGPRs
// (2x2x8 half8 = 128 regs); n weights in LDS. h state: LDS double-buffer,
// XOR chunk swizzle (chunk ^ row&7) for conflict-free MFMA A reads.
__global__ __launch_bounds__(512) __attribute__((amdgpu_waves_per_eu(2, 2)))
void k_gru(const _Float16* __restrict__ xi,
           const _Float16* __restrict__ whp,
           const float* __restrict__ bhhf,
           const float* __restrict__ bhhr,
           _Float16* __restrict__ out) {
  extern __shared__ _Float16 smem[];
  _Float16* nlds = smem;                  // 16*8*512 = 65536 halves (128 KB)
  _Float16* hb0  = smem + 65536;          // 16 rows * 256 = 4096
  _Float16* hb1  = smem + 69632;          // 4096  -> total 147456 B

  const int tid = threadIdx.x, w = tid >> 6, ln = tid & 63;
  const int jl = ln & 15, q = ln >> 4;
  const int bt = blockIdx.x, dir = blockIdx.y;
  const float* bhh = dir ? bhhr : bhhf;

  // ---- weights: r,z pinned VGPR; n -> LDS ----
  half8 wrz[2][2][8];   // [tile][gate r/z][kf] = 32 half8 = 128 VGPRs
#pragma unroll
  for (int tt = 0; tt < 2; ++tt) {
    const _Float16* wb = whp + ((size_t)(dir * 16 + w * 2 + tt)) * 12288;
#pragma unroll
    for (int g = 0; g < 2; ++g)
#pragma unroll
      for (int kf = 0; kf < 8; ++kf) {
        wrz[tt][g][kf] = *(const half8*)(wb + g * 4096 + kf * 512 + ln * 8);
        asm volatile("" : "+v"(wrz[tt][g][kf]));   // pin: opaque def, no remat
      }
#pragma unroll
    for (int kf = 0; kf < 8; ++kf)
      *(half8*)(nlds + ((w * 2 + tt) * 8 + kf) * 512 + ln * 8) =
          *(const half8*)(wb + 2 * 4096 + kf * 512 + ln * 8);
  }
  float bhn[2];
#pragma unroll
  for (int tt = 0; tt < 2; ++tt) bhn[tt] = bhh[512 + w * 32 + tt * 16 + jl];

  for (int i = tid; i < 4096; i += 512) hb0[i] = (_Float16)0.f;

  // ---- xi pointers (per batch-row rg) + preload t0 ----
  const long long t0 = dir ? (SEQ - 1) : 0;
  const int xstep = dir ? -NG : NG;
  const int wcol = w * 32 + jl;
  const _Float16* xp[4];
#pragma unroll
  for (int rg = 0; rg < 4; ++rg)
    xp[rg] = xi + ((size_t)((bt * 16 + q * 4 + rg) * SEQ) + t0) * NG + dir * 768;

  _Float16 cx[2][3][4];   // current step xi [tile][gate][rg]
#pragma unroll
  for (int rg = 0; rg < 4; ++rg)
#pragma unroll
    for (int tt = 0; tt < 2; ++tt)
#pragma unroll
      for (int g = 0; g < 3; ++g)
        cx[tt][g][rg] = xp[rg][g * 256 + wcol + tt * 16];

  // ---- coalesced out-store mapping (1 step delayed) ----
  const int orow = tid >> 5, oc = tid & 31;
  _Float16* op = out + ((size_t)((bt * 16 + orow) * SEQ) + t0) * 512 + dir * 256 + oc * 8;
  const int ostep = dir ? -512 : 512;
  const int oaddr = orow * 256 + ((oc ^ (orow & 7)) << 3);   // swizzled LDS src

  __syncthreads();   // nlds + hb0 ready

  for (int t = 0; t < SEQ; ++t) {
    const _Float16* hr = (t & 1) ? hb1 : hb0;
    _Float16*       hw = (t & 1) ? hb0 : hb1;

    // prefetch xi(t+1) into regs (latency hidden under MFMA)
    _Float16 nx[2][3][4];
    if (t < SEQ - 1) {
#pragma unroll
      for (int rg = 0; rg < 4; ++rg) {
        const _Float16* p = xp[rg] + xstep;
#pragma unroll
        for (int tt = 0; tt < 2; ++tt)
#pragma unroll
          for (int g = 0; g < 3; ++g)
            nx[tt][g][rg] = p[g * 256 + wcol + tt * 16];
      }
    }
    // store h(t-1) to global (reads hr, which holds h(t-1))
    if (t > 0) {
      *(half8*)op = *(const half8*)(hr + oaddr);
      op += ostep;
    }

    fx4 acc[2][3];
#pragma unroll
    for (int tt = 0; tt < 2; ++tt)
#pragma unroll
      for (int g = 0; g < 3; ++g) acc[tt][g] = (fx4){0.f, 0.f, 0.f, 0.f};

#pragma unroll
    for (int kf = 0; kf < 8; ++kf) {
      int cc = kf * 4 + q;                 // k-chunk 0..31
      half8 a = *(const half8*)(hr + jl * 256 + ((cc ^ (jl & 7)) << 3));
      half8 nb0 = *(const half8*)(nlds + ((w * 2 + 0) * 8 + kf) * 512 + ln * 8);
      half8 nb1 = *(const half8*)(nlds + ((w * 2 + 1) * 8 + kf) * 512 + ln * 8);
      acc[0][0] = __builtin_amdgcn_mfma_f32_16x16x32_f16(a, wrz[0][0][kf], acc[0][0], 0, 0, 0);
      acc[0][1] = __builtin_amdgcn_mfma_f32_16x16x32_f16(a, wrz[0][1][kf], acc[0][1], 0, 0, 0);
      acc[0][2] = __builtin_amdgcn_mfma_f32_16x16x32_f16(a, nb0,           acc[0][2], 0, 0, 0);
      acc[1][0] = __builtin_amdgcn_mfma_f32_16x16x32_f16(a, wrz[1][0][kf], acc[1][0], 0, 0, 0);
      acc[1][1] = __builtin_amdgcn_mfma_f32_16x16x32_f16(a, wrz[1][1][kf], acc[1][1], 0, 0, 0);
      acc[1][2] = __builtin_amdgcn_mfma_f32_16x16x32_f16(a, nb1,           acc[1][2], 0, 0, 0);
    }

#pragma unroll
    for (int tt = 0; tt < 2; ++tt) {
      const int col = wcol + tt * 16;
      const int chunk = col >> 3;
#pragma unroll
      for (int rg = 0; rg < 4; ++rg) {
        const int rr = q * 4 + rg;
        const int haddr = rr * 256 + ((chunk ^ (rr & 7)) << 3) + (jl & 7);
        float ir  = (float)cx[tt][0][rg];   // has bih_r + bhh_r
        float iz  = (float)cx[tt][1][rg];   // has bih_z + bhh_z
        float inn = (float)cx[tt][2][rg];   // has bih_n
        float rv = __builtin_amdgcn_rcpf(1.f + __expf(-(acc[tt][0][rg] + ir)));
        float zv = __builtin_amdgcn_rcpf(1.f + __expf(-(acc[tt][1][rg] + iz)));
        float gn = inn + rv * (acc[tt][2][rg] + bhn[tt]);
        float e2 = __expf(2.f * gn);
        float nn = 1.f - 2.f * __builtin_amdgcn_rcpf(e2 + 1.f);  // tanh, inf-safe
        float hp = (float)hr[haddr];
        float h = zv * (hp - nn) + nn;
        hw[haddr] = (_Float16)h;
      }
    }
#pragma unroll
    for (int rg = 0; rg < 4; ++rg) {
      xp[rg] += (t < SEQ - 1) ? xstep : 0;
#pragma unroll
      for (int tt = 0; tt < 2; ++tt)
#pragma unroll
        for (int g = 0; g < 3; ++g) cx[tt][g][rg] = nx[tt][g][rg];
    }
    __syncthreads();   // h(t) visible; hr reads done before next overwrite
  }
  // flush h(SEQ-1): written at t=199 into hb0
  *(half8*)op = *(const half8*)(hb0 + oaddr);
}

// ---------------------------- heads ----------------------------------------

__global__ __launch_bounds__(256) void k_heads1(const _Float16* __restrict__ out,
                                                const float* __restrict__ fc1w,
                                                const float* __restrict__ fc1b,
                                                const float* __restrict__ fc2w,
                                                const float* __restrict__ fc2b,
                                                float* __restrict__ y,
                                                float* __restrict__ y2) {
  int gw = (blockIdx.x * 256 + threadIdx.x) >> 6;
  int ln = threadIdx.x & 63;
  int b = gw / SEQ, t = gw - b * SEQ;
  half8 ov = *(const half8*)(out + (size_t)gw * 512 + ln * 8);
  float o[8];
#pragma unroll
  for (int i = 0; i < 8; ++i) o[i] = (float)ov[i];

  float4 w1a = *(const float4*)(fc1w + ln * 8);
  float4 w1b = *(const float4*)(fc1w + ln * 8 + 4);
  float s1 = o[0]*w1a.x + o[1]*w1a.y + o[2]*w1a.z + o[3]*w1a.w
           + o[4]*w1b.x + o[5]*w1b.y + o[6]*w1b.z + o[7]*w1b.w;
  float s2[10];
#pragma unroll
  for (int c = 0; c < 10; ++c) {
    float4 wa = *(const float4*)(fc2w + c * 512 + ln * 8);
    float4 wbv = *(const float4*)(fc2w + c * 512 + ln * 8 + 4);
    s2[c] = o[0]*wa.x + o[1]*wa.y + o[2]*wa.z + o[3]*wa.w
          + o[4]*wbv.x + o[5]*wbv.y + o[6]*wbv.z + o[7]*wbv.w;
  }
#pragma unroll
  for (int m = 32; m; m >>= 1) {
    s1 += __shfl_xor(s1, m);
#pragma unroll
    for (int c = 0; c < 10; ++c) s2[c] += __shfl_xor(s2[c], m);
  }
  if (ln == 0) {
    y[gw] = s1 + fc1b[0];
    float* y2p = y2 + (size_t)b * 2000 + t * 10;
#pragma unroll
    for (int c = 0; c < 10; ++c) y2p[c] = s2[c] + fc2b[c];
  }
}

__device__ __forceinline__ float blkRedMax(float v, float* red, int tid) {
#pragma unroll
  for (int m = 32; m; m >>= 1) v = fmaxf(v, __shfl_xor(v, m));
  __syncthreads();
  if ((tid & 63) == 0) red[tid >> 6] = v;
  __syncthreads();
  return fmaxf(fmaxf(red[0], red[1]), fmaxf(red[2], red[3]));
}
__device__ __forceinline__ float blkRedSum(float v, float* red, int tid) {
#pragma unroll
  for (int m = 32; m; m >>= 1) v += __shfl_xor(v, m);
  __syncthreads();
  if ((tid & 63) == 0) red[tid >> 6] = v;
  __syncthreads();
  return red[0] + red[1] + red[2] + red[3];
}

__global__ __launch_bounds__(256) void k_heads2(const float* __restrict__ y,
                                                const float* __restrict__ y2,
                                                float* __restrict__ y3) {
  __shared__ float sp[SEQ];
  __shared__ float se[2000];
  __shared__ float red[4];
  int b = blockIdx.x, tid = threadIdx.x;

  float v = (tid < SEQ) ? y[(size_t)b * SEQ + tid] : -3.0e38f;
  float mx = blkRedMax(v, red, tid);
  float e = (tid < SEQ) ? __expf(v - mx) : 0.f;
  float sum = blkRedSum(e, red, tid);
  if (tid < SEQ) sp[tid] = e / (sum * 10.f);

  float vv[8];
  float lm = -3.0e38f;
#pragma unroll
  for (int r = 0; r < 8; ++r) {
    int k = tid + r * 256;
    vv[r] = (k < 2000) ? y2[(size_t)b * 2000 + k] : -3.0e38f;
    lm = fmaxf(lm, vv[r]);
  }
  float mx2 = blkRedMax(lm, red, tid);
  float ls = 0.f;
#pragma unroll
  for (int r = 0; r < 8; ++r) {
    int k = tid + r * 256;
    if (k < 2000) { float ee = __expf(vv[r] - mx2); se[k] = ee; ls += ee; }
  }
  float sum2 = blkRedSum(ls, red, tid);
  __syncthreads();
  float inv = 1.f / sum2;
#pragma unroll
  for (int r = 0; r < 8; ++r) {
    int k = tid + r * 256;
    if (k < 2000) y3[(size_t)b * 2000 + k] = se[k] * inv + sp[k / 10];
  }
}

// ---------------------------- launch ---------------------------------------

extern "C" void kernel_launch(void* const* d_in, const int* in_sizes, int n_in,
                              void* d_out, int out_size, void* d_ws, size_t ws_size,
                              hipStream_t stream) {
  const float* x     = (const float*)d_in[0];
  const float* wih0  = (const float*)d_in[1];
  const float* whh0  = (const float*)d_in[2];
  const float* bih0  = (const float*)d_in[3];
  const float* bhh0  = (const float*)d_in[4];
  const float* wih0r = (const float*)d_in[5];
  const float* whh0r = (const float*)d_in[6];
  const float* bih0r = (const float*)d_in[7];
  const float* bhh0r = (const float*)d_in[8];
  const float* wih1  = (const float*)d_in[9];
  const float* whh1  = (const float*)d_in[10];
  const float* bih1  = (const float*)d_in[11];
  const float* bhh1  = (const float*)d_in[12];
  const float* wih1r = (const float*)d_in[13];
  const float* whh1r = (const float*)d_in[14];
  const float* bih1r = (const float*)d_in[15];
  const float* bhh1r = (const float*)d_in[16];
  const float* fc1w  = (const float*)d_in[17];
  const float* fc1b  = (const float*)d_in[18];
  const float* fc2w  = (const float*)d_in[19];
  const float* fc2b  = (const float*)d_in[20];

  char* ws = (char*)d_ws;
  _Float16* xh    = (_Float16*)(ws + 0);
  _Float16* xi    = (_Float16*)(ws + 52428800);
  _Float16* l0    = (_Float16*)(ws + 209715200);
  _Float16* outh  = (_Float16*)(ws + 262144000);
  _Float16* wcat0 = (_Float16*)(ws + 314572800);
  _Float16* wcat1 = (_Float16*)(ws + 316145664);
  _Float16* whp0  = (_Float16*)(ws + 317718528);
  _Float16* whp1  = (_Float16*)(ws + 318504960);
  float*    bcat0 = (float*)(ws + 319291392);
  float*    bcat1 = (float*)(ws + 319297536);

  float* y  = (float*)d_out;
  float* y2 = (float*)d_out + 51200;
  float* y3 = (float*)d_out + 563200;

  k_cast_x<<<25600, 256, 0, stream>>>((const float4*)x, (half4v*)xh, 6553600);
  k_prep_wih<<<3072, 256, 0, stream>>>(wih0, wih0r, bih0, bih0r, bhh0, bhh0r, wcat0, bcat0);
  k_prep_wih<<<3072, 256, 0, stream>>>(wih1, wih1r, bih1, bih1r, bhh1, bhh1r, wcat1, bcat1);
  k_prep_whh<<<1536, 256, 0, stream>>>(whh0, whh0r, whp0);
  k_prep_whh<<<1536, 256, 0, stream>>>(whh1, whh1r, whp1);

  hipFuncSetAttribute(reinterpret_cast<const void*>(k_gru),
                      hipFuncAttributeMaxDynamicSharedMemorySize, 147456);

  k_gemm<<<dim3(400, 12), 256, 0, stream>>>(xh, wcat0, bcat0, xi);
  k_gru<<<dim3(16, 2), 512, 147456, stream>>>(xi, whp0, bhh0, bhh0r, l0);
  k_gemm<<<dim3(400, 12), 256, 0, stream>>>(l0, wcat1, bcat1, xi);
  k_gru<<<dim3(16, 2), 512, 147456, stream>>>(xi, whp1, bhh1, bhh1r, outh);
  k_heads1<<<12800, 256, 0, stream>>>(outh, fc1w, fc1b, fc2w, fc2b, y, y2);
  k_heads2<<<256, 256, 0, stream>>>(y, y2, y3);
}

// Round 6
// 1256.871 us; speedup vs baseline: 1.8095x; 1.0770x over previous
//
#include <hip/hip_runtime.h>

// ---------------------------------------------------------------------------
// Bidirectional 2-layer GRU (B=256, L=200, IN=512, H=256) + FC heads.
// R6: k_gru keeps R5 topology (8 waves, r/z pinned VGPR, n in LDS) and adds:
//   - custom barrier (s_waitcnt lgkmcnt(0); s_barrier): xi prefetch VMEM
//     stays in flight across steps (syncthreads was draining vmcnt(0) ->
//     exposed ~900cyc HBM latency per step)
//   - hprev carried in registers (kills per-step LDS hp re-reads)
//   - xi + bhn folded into MFMA accumulator init (kills epilogue adds)
// ---------------------------------------------------------------------------

typedef _Float16 half8 __attribute__((ext_vector_type(8)));
typedef _Float16 half4v __attribute__((ext_vector_type(4)));
typedef float fx4 __attribute__((ext_vector_type(4)));

#define BATCH 256
#define SEQ   200
#define HID   256
#define MROWS (BATCH*SEQ)   // 51200
#define NG    1536          // 3H * 2 directions
#define KDIM  512

__device__ __forceinline__ void gload_lds16(const _Float16* g, _Float16* l) {
  __builtin_amdgcn_global_load_lds((const __attribute__((address_space(1))) void*)g,
                                   (__attribute__((address_space(3))) void*)l, 16, 0, 0);
}

// Barrier that drains only LDS ops (lgkmcnt), NOT vmcnt: global prefetch
// loads stay outstanding across the step boundary.
__device__ __forceinline__ void gru_barrier() {
  asm volatile("s_waitcnt lgkmcnt(0)\n\ts_barrier" ::: "memory");
}

// ---------------------------- prep kernels ---------------------------------

__global__ __launch_bounds__(256) void k_cast_x(const float4* __restrict__ x,
                                                half4v* __restrict__ xh, int n4) {
  int i = blockIdx.x * 256 + threadIdx.x;
  if (i < n4) {
    float4 v = x[i];
    half4v o;
    o[0] = (_Float16)v.x; o[1] = (_Float16)v.y; o[2] = (_Float16)v.z; o[3] = (_Float16)v.w;
    xh[i] = o;
  }
}

// Concat input-projection weights [1536][512] fp16; bias = bih + (bhh for r,z only)
__global__ __launch_bounds__(256) void k_prep_wih(const float* __restrict__ wf,
                                                  const float* __restrict__ wr,
                                                  const float* __restrict__ bf_,
                                                  const float* __restrict__ br_,
                                                  const float* __restrict__ bhf,
                                                  const float* __restrict__ bhr,
                                                  _Float16* __restrict__ wcat,
                                                  float* __restrict__ bcat) {
  int idx = blockIdx.x * 256 + threadIdx.x;     // < 1536*512
  int n = idx >> 9;
  float v = (n < 768) ? wf[idx] : wr[idx - 768 * 512];
  wcat[idx] = (_Float16)v;
  if (idx < 1536) {
    float b;
    if (idx < 768) b = bf_[idx] + ((idx < 512) ? bhf[idx] : 0.f);
    else { int i2 = idx - 768; b = br_[i2] + ((i2 < 512) ? bhr[i2] : 0.f); }
    bcat[idx] = b;
  }
}

// Pack w_hh into MFMA B-fragment order: [dir][T(16)][gate(3)][kf(8)][lane(64)][i(8)]
__global__ __launch_bounds__(256) void k_prep_whh(const float* __restrict__ whf,
                                                  const float* __restrict__ whr,
                                                  _Float16* __restrict__ whp) {
  int e = blockIdx.x * 256 + threadIdx.x;       // < 2*196608
  int dir = e / 196608;
  int r = e - dir * 196608;
  int w = r / 12288;  int r2 = r - w * 12288;
  int gate = r2 >> 12; int r3 = r2 & 4095;
  int kf = r3 >> 9;    int r4 = r3 & 511;
  int lane = r4 >> 3;  int i = r4 & 7;
  int row = gate * 256 + w * 16 + (lane & 15);
  int col = kf * 32 + (lane >> 4) * 8 + i;
  const float* src = dir ? whr : whf;
  whp[e] = (_Float16)src[row * 256 + col];
}

// ---------------------------- xi GEMM (m97 structure) ----------------------
__global__ __launch_bounds__(256) void k_gemm(const _Float16* __restrict__ A,
                                              const _Float16* __restrict__ Wt,
                                              const float* __restrict__ bias,
                                              _Float16* __restrict__ C) {
  __shared__ __align__(16) _Float16 As[128 * 32];
  __shared__ __align__(16) _Float16 Bs[128 * 32];
  const int tid = threadIdx.x;
  const int wv = tid >> 6, ln = tid & 63;
  const int wm = wv >> 1, wn = wv & 1;
  const int jl = ln & 15, q = ln >> 4;
  const int m0 = blockIdx.x * 128, n0 = blockIdx.y * 128;

  const int r0 = tid >> 2, k80 = (tid & 3) * 8;
  const int r1 = r0 + 64;

  fx4 acc[4][4];
#pragma unroll
  for (int a = 0; a < 4; ++a)
#pragma unroll
    for (int b = 0; b < 4; ++b) acc[a][b] = (fx4){0.f, 0.f, 0.f, 0.f};

  for (int kk = 0; kk < KDIM; kk += 32) {
    gload_lds16(A  + (size_t)(m0 + r0) * KDIM + kk + k80, As + tid * 8);
    gload_lds16(A  + (size_t)(m0 + r1) * KDIM + kk + k80, As + (tid + 256) * 8);
    gload_lds16(Wt + (size_t)(n0 + r0) * KDIM + kk + k80, Bs + tid * 8);
    gload_lds16(Wt + (size_t)(n0 + r1) * KDIM + kk + k80, Bs + (tid + 256) * 8);
    __syncthreads();
    half8 af[4], bfr[4];
#pragma unroll
    for (int mt = 0; mt < 4; ++mt)
      af[mt] = *(const half8*)(As + (wm * 64 + mt * 16 + jl) * 32 + q * 8);
#pragma unroll
    for (int nt = 0; nt < 4; ++nt)
      bfr[nt] = *(const half8*)(Bs + (wn * 64 + nt * 16 + jl) * 32 + q * 8);
#pragma unroll
    for (int mt = 0; mt < 4; ++mt)
#pragma unroll
      for (int nt = 0; nt < 4; ++nt)
        acc[mt][nt] = __builtin_amdgcn_mfma_f32_16x16x32_f16(af[mt], bfr[nt], acc[mt][nt], 0, 0, 0);
    __syncthreads();
  }

  float bsv[4];
#pragma unroll
  for (int nt = 0; nt < 4; ++nt) bsv[nt] = bias[n0 + wn * 64 + nt * 16 + jl];

  for (int mt = 0; mt < 4; ++mt) {
#pragma unroll
    for (int nt = 0; nt < 4; ++nt)
#pragma unroll
      for (int rg = 0; rg < 4; ++rg)
        As[(wm * 16 + q * 4 + rg) * 128 + wn * 64 + nt * 16 + jl] =
            (_Float16)(acc[mt][nt][rg] + bsv[nt]);
    __syncthreads();
#pragma unroll
    for (int i = 0; i < 2; ++i) {
      int idx = i * 256 + tid;
      int rl = idx >> 4, c8 = idx & 15;
      int grow = m0 + (rl >> 4) * 64 + mt * 16 + (rl & 15);
      *(half8*)(C + (size_t)grow * NG + n0 + c8 * 8) = *(const half8*)(As + rl * 128 + c8 * 8);
    }
    __syncthreads();
  }
}

// ---------------------------- GRU recurrence -------------------------------
// 32 blocks (16 batch-tiles x 2 dirs) x 512 threads (8 waves, 2/SIMD).
// Wave w owns hidden [32w, 32w+32) = 2 tiles. r,z weights pinned in VGPRs;
// n weights in LDS. h: LDS double-buffer, XOR chunk swizzle; hprev in regs;
// xi folded into acc init; custom lgkm-only barrier.
__global__ __launch_bounds__(512) __attribute__((amdgpu_waves_per_eu(2, 2)))
void k_gru(const _Float16* __restrict__ xi,
           const _Float16* __restrict__ whp,
           const float* __restrict__ bhhf,
           const float* __restrict__ bhhr,
           _Float16* __restrict__ out) {
  extern __shared__ _Float16 smem[];
  _Float16* nlds = smem;                  // 16*8*512 = 65536 halves (128 KB)
  _Float16* hb0  = smem + 65536;          // 16 rows * 256 = 4096
  _Float16* hb1  = smem + 69632;          // 4096  -> total 147456 B

  const int tid = threadIdx.x, w = tid >> 6, ln = tid & 63;
  const int jl = ln & 15, q = ln >> 4;
  const int bt = blockIdx.x, dir = blockIdx.y;
  const float* bhh = dir ? bhhr : bhhf;

  // ---- weights: r,z pinned VGPR; n -> LDS ----
  half8 wrz[2][2][8];   // [tile][gate r/z][kf] = 32 half8 = 128 VGPRs
#pragma unroll
  for (int tt = 0; tt < 2; ++tt) {
    const _Float16* wb = whp + ((size_t)(dir * 16 + w * 2 + tt)) * 12288;
#pragma unroll
    for (int g = 0; g < 2; ++g)
#pragma unroll
      for (int kf = 0; kf < 8; ++kf) {
        wrz[tt][g][kf] = *(const half8*)(wb + g * 4096 + kf * 512 + ln * 8);
        asm volatile("" : "+v"(wrz[tt][g][kf]));   // pin: opaque def, no remat
      }
#pragma unroll
    for (int kf = 0; kf < 8; ++kf)
      *(half8*)(nlds + ((w * 2 + tt) * 8 + kf) * 512 + ln * 8) =
          *(const half8*)(wb + 2 * 4096 + kf * 512 + ln * 8);
  }
  float bhn[2];
#pragma unroll
  for (int tt = 0; tt < 2; ++tt) bhn[tt] = bhh[512 + w * 32 + tt * 16 + jl];

  for (int i = tid; i < 4096; i += 512) hb0[i] = (_Float16)0.f;

  // ---- xi pointers (per batch-row rg) + preload t0 ----
  const long long t0 = dir ? (SEQ - 1) : 0;
  const int xstep = dir ? -NG : NG;
  const int wcol = w * 32 + jl;
  const _Float16* xp[4];
#pragma unroll
  for (int rg = 0; rg < 4; ++rg)
    xp[rg] = xi + ((size_t)((bt * 16 + q * 4 + rg) * SEQ) + t0) * NG + dir * 768;

  _Float16 cx[2][3][4];   // current step xi [tile][gate][rg]
#pragma unroll
  for (int rg = 0; rg < 4; ++rg)
#pragma unroll
    for (int tt = 0; tt < 2; ++tt)
#pragma unroll
      for (int g = 0; g < 3; ++g)
        cx[tt][g][rg] = xp[rg][g * 256 + wcol + tt * 16];

  // ---- coalesced out-store mapping (1 step delayed) ----
  const int orow = tid >> 5, oc = tid & 31;
  _Float16* op = out + ((size_t)((bt * 16 + orow) * SEQ) + t0) * 512 + dir * 256 + oc * 8;
  const int ostep = dir ? -512 : 512;
  const int oaddr = orow * 256 + ((oc ^ (orow & 7)) << 3);   // swizzled LDS src

  float hprev[2][4] = {{0.f,0.f,0.f,0.f},{0.f,0.f,0.f,0.f}};
  __syncthreads();   // nlds + hb0 ready (full barrier once)

  for (int t = 0; t < SEQ; ++t) {
    const _Float16* hr = (t & 1) ? hb1 : hb0;
    _Float16*       hw = (t & 1) ? hb0 : hb1;

    // prefetch xi(t+1) into regs; stays in flight across gru_barrier
    _Float16 nx[2][3][4];
    if (t < SEQ - 1) {
#pragma unroll
      for (int rg = 0; rg < 4; ++rg) {
        const _Float16* p = xp[rg] + xstep;
#pragma unroll
        for (int tt = 0; tt < 2; ++tt)
#pragma unroll
          for (int g = 0; g < 3; ++g)
            nx[tt][g][rg] = p[g * 256 + wcol + tt * 16];
      }
    }

    // acc init: r/z = xi (has all biases), n = bhh_n (xi_n added in epilogue)
    fx4 acc[2][3];
#pragma unroll
    for (int tt = 0; tt < 2; ++tt)
#pragma unroll
      for (int rg = 0; rg < 4; ++rg) {
        acc[tt][0][rg] = (float)cx[tt][0][rg];
        acc[tt][1][rg] = (float)cx[tt][1][rg];
        acc[tt][2][rg] = bhn[tt];
      }

    // store h(t-1) to global (hr holds h(t-1))
    if (t > 0) {
      *(half8*)op = *(const half8*)(hr + oaddr);
      op += ostep;
    }

#pragma unroll
    for (int kf = 0; kf < 8; ++kf) {
      int cc = kf * 4 + q;                 // k-chunk 0..31
      half8 a = *(const half8*)(hr + jl * 256 + ((cc ^ (jl & 7)) << 3));
      half8 nb0 = *(const half8*)(nlds + ((w * 2 + 0) * 8 + kf) * 512 + ln * 8);
      half8 nb1 = *(const half8*)(nlds + ((w * 2 + 1) * 8 + kf) * 512 + ln * 8);
      acc[0][0] = __builtin_amdgcn_mfma_f32_16x16x32_f16(a, wrz[0][0][kf], acc[0][0], 0, 0, 0);
      acc[0][1] = __builtin_amdgcn_mfma_f32_16x16x32_f16(a, wrz[0][1][kf], acc[0][1], 0, 0, 0);
      acc[0][2] = __builtin_amdgcn_mfma_f32_16x16x32_f16(a, nb0,           acc[0][2], 0, 0, 0);
      acc[1][0] = __builtin_amdgcn_mfma_f32_16x16x32_f16(a, wrz[1][0][kf], acc[1][0], 0, 0, 0);
      acc[1][1] = __builtin_amdgcn_mfma_f32_16x16x32_f16(a, wrz[1][1][kf], acc[1][1], 0, 0, 0);
      acc[1][2] = __builtin_amdgcn_mfma_f32_16x16x32_f16(a, nb1,           acc[1][2], 0, 0, 0);
    }

#pragma unroll
    for (int tt = 0; tt < 2; ++tt) {
      const int col = wcol + tt * 16;
      const int chunk = col >> 3;
#pragma unroll
      for (int rg = 0; rg < 4; ++rg) {
        const int rr = q * 4 + rg;
        const int haddr = rr * 256 + ((chunk ^ (rr & 7)) << 3) + (jl & 7);
        float rv = __builtin_amdgcn_rcpf(1.f + __expf(-acc[tt][0][rg]));
        float zv = __builtin_amdgcn_rcpf(1.f + __expf(-acc[tt][1][rg]));
        float gn = fmaf(rv, acc[tt][2][rg], (float)cx[tt][2][rg]);
        float e2 = __expf(2.f * gn);
        float nn = fmaf(-2.f, __builtin_amdgcn_rcpf(e2 + 1.f), 1.f);  // tanh
        float hp = hprev[tt][rg];
        float h = fmaf(zv, hp - nn, nn);
        hprev[tt][rg] = h;
        hw[haddr] = (_Float16)h;
      }
    }
#pragma unroll
    for (int rg = 0; rg < 4; ++rg) {
      xp[rg] += (t < SEQ - 1) ? xstep : 0;
#pragma unroll
      for (int tt = 0; tt < 2; ++tt)
#pragma unroll
        for (int g = 0; g < 3; ++g) cx[tt][g][rg] = nx[tt][g][rg];
    }
    gru_barrier();   // lgkm-only: h(t) visible, xi prefetch stays in flight
  }
  // flush h(SEQ-1): written at t=199 into hb0
  *(half8*)op = *(const half8*)(hb0 + oaddr);
}

// ---------------------------- heads ----------------------------------------

__global__ __launch_bounds__(256) void k_heads1(const _Float16* __restrict__ out,
                                                const float* __restrict__ fc1w,
                                                const float* __restrict__ fc1b,
                                                const float* __restrict__ fc2w,
                                                const float* __restrict__ fc2b,
                                                float* __restrict__ y,
                                                float* __restrict__ y2) {
  int gw = (blockIdx.x * 256 + threadIdx.x) >> 6;
  int ln = threadIdx.x & 63;
  int b = gw / SEQ, t = gw - b * SEQ;
  half8 ov = *(const half8*)(out + (size_t)gw * 512 + ln * 8);
  float o[8];
#pragma unroll
  for (int i = 0; i < 8; ++i) o[i] = (float)ov[i];

  float4 w1a = *(const float4*)(fc1w + ln * 8);
  float4 w1b = *(const float4*)(fc1w + ln * 8 + 4);
  float s1 = o[0]*w1a.x + o[1]*w1a.y + o[2]*w1a.z + o[3]*w1a.w
           + o[4]*w1b.x + o[5]*w1b.y + o[6]*w1b.z + o[7]*w1b.w;
  float s2[10];
#pragma unroll
  for (int c = 0; c < 10; ++c) {
    float4 wa = *(const float4*)(fc2w + c * 512 + ln * 8);
    float4 wbv = *(const float4*)(fc2w + c * 512 + ln * 8 + 4);
    s2[c] = o[0]*wa.x + o[1]*wa.y + o[2]*wa.z + o[3]*wa.w
          + o[4]*wbv.x + o[5]*wbv.y + o[6]*wbv.z + o[7]*wbv.w;
  }
#pragma unroll
  for (int m = 32; m; m >>= 1) {
    s1 += __shfl_xor(s1, m);
#pragma unroll
    for (int c = 0; c < 10; ++c) s2[c] += __shfl_xor(s2[c], m);
  }
  if (ln == 0) {
    y[gw] = s1 + fc1b[0];
    float* y2p = y2 + (size_t)b * 2000 + t * 10;
#pragma unroll
    for (int c = 0; c < 10; ++c) y2p[c] = s2[c] + fc2b[c];
  }
}

__device__ __forceinline__ float blkRedMax(float v, float* red, int tid) {
#pragma unroll
  for (int m = 32; m; m >>= 1) v = fmaxf(v, __shfl_xor(v, m));
  __syncthreads();
  if ((tid & 63) == 0) red[tid >> 6] = v;
  __syncthreads();
  return fmaxf(fmaxf(red[0], red[1]), fmaxf(red[2], red[3]));
}
__device__ __forceinline__ float blkRedSum(float v, float* red, int tid) {
#pragma unroll
  for (int m = 32; m; m >>= 1) v += __shfl_xor(v, m);
  __syncthreads();
  if ((tid & 63) == 0) red[tid >> 6] = v;
  __syncthreads();
  return red[0] + red[1] + red[2] + red[3];
}

__global__ __launch_bounds__(256) void k_heads2(const float* __restrict__ y,
                                                const float* __restrict__ y2,
                                                float* __restrict__ y3) {
  __shared__ float sp[SEQ];
  __shared__ float se[2000];
  __shared__ float red[4];
  int b = blockIdx.x, tid = threadIdx.x;

  float v = (tid < SEQ) ? y[(size_t)b * SEQ + tid] : -3.0e38f;
  float mx = blkRedMax(v, red, tid);
  float e = (tid < SEQ) ? __expf(v - mx) : 0.f;
  float sum = blkRedSum(e, red, tid);
  if (tid < SEQ) sp[tid] = e / (sum * 10.f);

  float vv[8];
  float lm = -3.0e38f;
#pragma unroll
  for (int r = 0; r < 8; ++r) {
    int k = tid + r * 256;
    vv[r] = (k < 2000) ? y2[(size_t)b * 2000 + k] : -3.0e38f;
    lm = fmaxf(lm, vv[r]);
  }
  float mx2 = blkRedMax(lm, red, tid);
  float ls = 0.f;
#pragma unroll
  for (int r = 0; r < 8; ++r) {
    int k = tid + r * 256;
    if (k < 2000) { float ee = __expf(vv[r] - mx2); se[k] = ee; ls += ee; }
  }
  float sum2 = blkRedSum(ls, red, tid);
  __syncthreads();
  float inv = 1.f / sum2;
#pragma unroll
  for (int r = 0; r < 8; ++r) {
    int k = tid + r * 256;
    if (k < 2000) y3[(size_t)b * 2000 + k] = se[k] * inv + sp[k / 10];
  }
}

// ---------------------------- launch ---------------------------------------

extern "C" void kernel_launch(void* const* d_in, const int* in_sizes, int n_in,
                              void* d_out, int out_size, void* d_ws, size_t ws_size,
                              hipStream_t stream) {
  const float* x     = (const float*)d_in[0];
  const float* wih0  = (const float*)d_in[1];
  const float* whh0  = (const float*)d_in[2];
  const float* bih0  = (const float*)d_in[3];
  const float* bhh0  = (const float*)d_in[4];
  const float* wih0r = (const float*)d_in[5];
  const float* whh0r = (const float*)d_in[6];
  const float* bih0r = (const float*)d_in[7];
  const float* bhh0r = (const float*)d_in[8];
  const float* wih1  = (const float*)d_in[9];
  const float* whh1  = (const float*)d_in[10];
  const float* bih1  = (const float*)d_in[11];
  const float* bhh1  = (const float*)d_in[12];
  const float* wih1r = (const float*)d_in[13];
  const float* whh1r = (const float*)d_in[14];
  const float* bih1r = (const float*)d_in[15];
  const float* bhh1r = (const float*)d_in[16];
  const float* fc1w  = (const float*)d_in[17];
  const float* fc1b  = (const float*)d_in[18];
  const float* fc2w  = (const float*)d_in[19];
  const float* fc2b  = (const float*)d_in[20];

  char* ws = (char*)d_ws;
  _Float16* xh    = (_Float16*)(ws + 0);
  _Float16* xi    = (_Float16*)(ws + 52428800);
  _Float16* l0    = (_Float16*)(ws + 209715200);
  _Float16* outh  = (_Float16*)(ws + 262144000);
  _Float16* wcat0 = (_Float16*)(ws + 314572800);
  _Float16* wcat1 = (_Float16*)(ws + 316145664);
  _Float16* whp0  = (_Float16*)(ws + 317718528);
  _Float16* whp1  = (_Float16*)(ws + 318504960);
  float*    bcat0 = (float*)(ws + 319291392);
  float*    bcat1 = (float*)(ws + 319297536);

  float* y  = (float*)d_out;
  float* y2 = (float*)d_out + 51200;
  float* y3 = (float*)d_out + 563200;

  k_cast_x<<<25600, 256, 0, stream>>>((const float4*)x, (half4v*)xh, 6553600);
  k_prep_wih<<<3072, 256, 0, stream>>>(wih0, wih0r, bih0, bih0r, bhh0, bhh0r, wcat0, bcat0);
  k_prep_wih<<<3072, 256, 0, stream>>>(wih1, wih1r, bih1, bih1r, bhh1, bhh1r, wcat1, bcat1);
  k_prep_whh<<<1536, 256, 0, stream>>>(whh0, whh0r, whp0);
  k_prep_whh<<<1536, 256, 0, stream>>>(whh1, whh1r, whp1);

  hipFuncSetAttribute(reinterpret_cast<const void*>(k_gru),
                      hipFuncAttributeMaxDynamicSharedMemorySize, 147456);

  k_gemm<<<dim3(400, 12), 256, 0, stream>>>(xh, wcat0, bcat0, xi);
  k_gru<<<dim3(16, 2), 512, 147456, stream>>>(xi, whp0, bhh0, bhh0r, l0);
  k_gemm<<<dim3(400, 12), 256, 0, stream>>>(l0, wcat1, bcat1, xi);
  k_gru<<<dim3(16, 2), 512, 147456, stream>>>(xi, whp1, bhh1, bhh1r, outh);
  k_heads1<<<12800, 256, 0, stream>>>(outh, fc1w, fc1b, fc2w, fc2b, y, y2);
  k_heads2<<<256, 256, 0, stream>>>(y, y2, y3);
}